// Round 4
// baseline (457.641 us; speedup 1.0000x reference)
//
#include <hip/hip_runtime.h>
#include <hip/hip_bf16.h>
#include <stdint.h>

// Problem constants (fixed by the reference)
#define N_EDGES   800000
#define N_NODESC  50000
#define HID       128

typedef __attribute__((ext_vector_type(8))) short bf16x8;  // 8 bf16 = 4 VGPRs (MFMA A/B frag)
typedef __attribute__((ext_vector_type(4))) float f32x4;   // MFMA C/D frag
typedef __attribute__((ext_vector_type(4))) unsigned int u32x4;

__device__ __forceinline__ short f2bf(float f) {
    union { float f; uint32_t u; } v; v.f = f;
    uint32_t r = v.u + 0x7FFFu + ((v.u >> 16) & 1u);   // round-to-nearest-even
    return (short)(r >> 16);
}

// pack two f32 -> bf16x2 (RNE) via native v_cvt_pk_bf16_f32 on gfx950
__device__ __forceinline__ uint32_t packbf2(float lo, float hi) {
    float2 t; t.x = lo; t.y = hi;
    __hip_bfloat162 h = __float22bfloat162_rn(t);
    uint32_t u;
    __builtin_memcpy(&u, &h, 4);       // __hip_bfloat162 not trivially copyable -> memcpy pun
    return u;
}

// packed bf16x2 (a+b) then relu:
//   __hadd2 -> native v_pk_add_bf16 (one RNE rounding);  relu via sign-mask, exact.
__device__ __forceinline__ uint32_t addrelu2(uint32_t a, uint32_t b) {
    __hip_bfloat162 ha, hb;
    __builtin_memcpy(&ha, &a, 4);
    __builtin_memcpy(&hb, &b, 4);
    __hip_bfloat162 s = __hadd2(ha, hb);
    uint32_t x;
    __builtin_memcpy(&x, &s, 4);
    uint32_t neg = (x & 0x80008000u) >> 15;      // 1 at bit0/bit16 where half negative
    return x & ~(neg * 0xFFFFu);                 // zero negative halves
}
__device__ __forceinline__ bf16x8 addrelu8(u32x4 p, u32x4 q) {
    u32x4 r;
    #pragma unroll
    for (int j = 0; j < 4; ++j) r[j] = addrelu2(p[j], q[j]);
    bf16x8 out;
    __builtin_memcpy(&out, &r, 16);
    return out;
}

// ---------------- workspace layout ----------------
// PQ  : bf16 [50000][1024]  (cols 0..511 = emb@W1_top + b1 "P'", 512..1023 = emb@W1_bot "Q")
// W1s : bf16 frag-major, 4*64 frags x 64 lanes x 8   (B-frags of W1cat [128,1024])
// W2s : bf16 frag-major, 16*8 frags x 64 lanes x 8   (B-frags of W2 [512,128])
// cnt : int[8][50176]  XCD-SEGMENTED histogram -> (after in-place scan) cursor.
//       R3 post-mortem: the flat 200 KB histogram put 16 bins per 64 B line, hit by
//       all 8 XCDs -> per-atomic line ping-pong ~= the 135 us chain.  seg = blockIdx&7
//       (round-robin block->XCD) + seg-major layout keeps atomic lines XCD-local.
//       Sort order becomes (seg, col): 8 col-sorted runs — identical per-tile locality.
// bsum: int[2048]      scanA block totals (1568 used)
// spk : uint[800000]   (seg,col)-sorted edges, packed (row<<16 | col)
// pos : int[800000]    sorted position of original edge e (written coalesced)
// tmp : float[800000]  edge-kernel results in SORTED order (coalesced writes)
#define PQ_OFF    0UL
#define W1S_OFF   102400000UL                 // 50000*1024*2
#define W2S_OFF   (W1S_OFF + 262144UL)        // + 128*1024*2
#define CNT_OFF   (W2S_OFF + 131072UL)        // 102,793,216 ; 8*50176*4 = 1,605,632 B
#define BSUM_OFF  (CNT_OFF + 1605632UL)       // 104,398,848
#define SPK_OFF   (BSUM_OFF + 8192UL)         // 104,407,040
#define POS_OFF   (SPK_OFF + 3200000UL)       // 107,607,040
#define TMP_OFF   (POS_OFF + 3200000UL)       // 110,807,040
// total ws: 114,007,040 bytes (+1.2 MB vs R3's 112.8 MB)

#define NBINS     50176                       // 196*256 (padded)
#define NSEG      8
#define SCAN_N    (NSEG * NBINS)              // 401408 = 1568 * 256
#define SCANA_BLOCKS 1568

// ============ kernel 0: weight convert + B-fragment swizzle ============
// B-frag for 16x16x32 bf16: lane l holds B[k = kc*32 + (l>>4)*8 + j][n = nt*16 + (l&15)], j=0..7
__global__ __launch_bounds__(256) void swizzle_kernel(const float* __restrict__ W1,
                                                      const float* __restrict__ W2,
                                                      short* __restrict__ W1s,
                                                      short* __restrict__ W2s) {
    int t = blockIdx.x * 256 + threadIdx.x;
    int lane = t & 63;
    int kq = lane >> 4;       // 0..3
    int nn = lane & 15;
    if (t < 16384) {          // W1cat: K=128, N=1024 -> kc 0..3, nt 0..63
        int frag = t >> 6;
        int kc = frag >> 6;
        int nt = frag & 63;
        int n = nt * 16 + nn;
        int kbase = kc * 32 + kq * 8;
        bf16x8 v;
        #pragma unroll
        for (int j = 0; j < 8; ++j) {
            int k = kbase + j;
            float f = (n < 512) ? W1[k * 512 + n] : W1[(128 + k) * 512 + (n - 512)];
            v[j] = f2bf(f);
        }
        *(bf16x8*)(W1s + frag * 512 + lane * 8) = v;
    } else if (t < 24576) {   // W2: K=512, N=128 -> kc 0..15, nt 0..7
        int t2 = t - 16384;
        int frag = t2 >> 6;
        int kc = frag >> 3;
        int nt = frag & 7;
        int n = nt * 16 + nn;
        int kbase = kc * 32 + kq * 8;
        bf16x8 v;
        #pragma unroll
        for (int j = 0; j < 8; ++j) v[j] = f2bf(W2[(kbase + j) * HID + n]);
        *(bf16x8*)(W2s + frag * 512 + lane * 8) = v;
    }
}

// ============ kernel 1: PQ = emb @ W1cat (+b1 on P half) ============
// grid 3125 x 256: block = 16 node rows, 4 waves each owning a 256-col slice.
__global__ __launch_bounds__(256) void precompute_kernel(const float* __restrict__ emb,
                                                         const short* __restrict__ W1s,
                                                         const float* __restrict__ b1,
                                                         short* __restrict__ PQ) {
    // per-wave tile: 16 rows x 256 cols bf16; row stride 272 shorts = 544 B
    __shared__ short tile[4][16][272];
    int lane = threadIdx.x & 63;
    int w = threadIdx.x >> 6;
    int nb = blockIdx.x * 16;
    int m = lane & 15;
    int kq = lane >> 4;

    const float* arow = emb + (size_t)(nb + m) * 128 + kq * 8;

    f32x4 acc[16];
    #pragma unroll
    for (int i = 0; i < 16; ++i) acc[i] = (f32x4){0.f, 0.f, 0.f, 0.f};

    #pragma unroll
    for (int kc = 0; kc < 4; ++kc) {
        f32x4 x0 = *(const f32x4*)(arow + kc * 32);
        f32x4 x1 = *(const f32x4*)(arow + kc * 32 + 4);
        u32x4 au;
        au[0] = packbf2(x0[0], x0[1]); au[1] = packbf2(x0[2], x0[3]);
        au[2] = packbf2(x1[0], x1[1]); au[3] = packbf2(x1[2], x1[3]);
        bf16x8 a;
        __builtin_memcpy(&a, &au, 16);
        #pragma unroll
        for (int nt = 0; nt < 16; ++nt) {
            int frag = kc * 64 + (w * 16 + nt);
            bf16x8 b = *(const bf16x8*)(W1s + frag * 512 + lane * 8);
            acc[nt] = __builtin_amdgcn_mfma_f32_16x16x32_bf16(a, b, acc[nt], 0, 0, 0);
        }
    }

    // C/D layout: col = lane&15, row = (lane>>4)*4 + r.  Fold b1 into the P half (n<512).
    #pragma unroll
    for (int nt = 0; nt < 16; ++nt) {
        int n = w * 256 + nt * 16 + m;
        float bias = (n < 512) ? b1[n] : 0.0f;
        #pragma unroll
        for (int r = 0; r < 4; ++r)
            tile[w][kq * 4 + r][nt * 16 + m] = f2bf(acc[nt][r] + bias);
    }

    // Read back row-major and store coalesced: 16 B per lane.
    #pragma unroll
    for (int s = 0; s < 8; ++s) {
        int row = s * 2 + (lane >> 5);
        int chunk = lane & 31;
        bf16x8 v = *(const bf16x8*)(&tile[w][row][chunk * 8]);
        *(bf16x8*)(PQ + (size_t)(nb + row) * 1024 + w * 256 + chunk * 8) = v;
    }
}

// ============ XCD-segmented counting sort of edges by (seg, col) ============

__global__ __launch_bounds__(256) void hist_kernel(const int* __restrict__ ei,
                                                   int* __restrict__ counts) {
    int e = blockIdx.x * 256 + threadIdx.x;                // grid 3125
    int seg = blockIdx.x & 7;                              // block->XCD is round-robin
    atomicAdd(&counts[seg * NBINS + ei[e]], 1);            // XCD-local line
}

// scanA: in-place exclusive scan per 256-chunk of counts; chunk totals -> bsum
__global__ __launch_bounds__(256) void scanA_kernel(int* __restrict__ counts,
                                                    int* __restrict__ bsum) {
    __shared__ int sm[256];
    int t = threadIdx.x;
    int i = blockIdx.x * 256 + t;                          // grid 1568
    int v = counts[i];
    sm[t] = v;
    __syncthreads();
    #pragma unroll
    for (int off = 1; off < 256; off <<= 1) {
        int y = (t >= off) ? sm[t - off] : 0;
        __syncthreads();
        sm[t] += y;
        __syncthreads();
    }
    counts[i] = sm[t] - v;                                 // exclusive within chunk
    if (t == 255) bsum[blockIdx.x] = sm[t];
}

// scanB: exclusive scan of the 1568 chunk totals, single block.
// thread t owns 7 consecutive totals; LDS-scan of per-thread sums; serial rewrite.
__global__ __launch_bounds__(256) void scanB_kernel(int* __restrict__ bsum) {
    __shared__ int sm[256];
    int t = threadIdx.x;
    int local = 0;
    #pragma unroll
    for (int j = 0; j < 7; ++j) {
        int idx = t * 7 + j;
        local += (idx < SCANA_BLOCKS) ? bsum[idx] : 0;
    }
    sm[t] = local;
    __syncthreads();
    #pragma unroll
    for (int off = 1; off < 256; off <<= 1) {
        int y = (t >= off) ? sm[t - off] : 0;
        __syncthreads();
        sm[t] += y;
        __syncthreads();
    }
    int running = sm[t] - local;                           // exclusive base for this chunk
    #pragma unroll
    for (int j = 0; j < 7; ++j) {
        int idx = t * 7 + j;
        if (idx < SCANA_BLOCKS) {
            int c = bsum[idx];
            bsum[idx] = running;
            running += c;
        }
    }
}

// scanC: add chunk bases back -> counts becomes the global cursor array
__global__ __launch_bounds__(256) void scanC_kernel(int* __restrict__ counts,
                                                    const int* __restrict__ bsum) {
    counts[blockIdx.x * 256 + threadIdx.x] += bsum[blockIdx.x];   // grid 1568
}

__global__ __launch_bounds__(256) void scatter_kernel(const int* __restrict__ ei,
                                                      int* __restrict__ cursor,
                                                      unsigned int* __restrict__ spk,
                                                      int* __restrict__ pos) {
    int e = blockIdx.x * 256 + threadIdx.x;                // grid 3125
    int seg = blockIdx.x & 7;                              // must match hist_kernel
    int c = ei[e];
    int r = ei[N_EDGES + e];
    int p = atomicAdd(&cursor[seg * NBINS + c], 1);        // XCD-local line
    spk[p] = ((unsigned int)r << 16) | (unsigned int)c;    // 50000 < 2^16: both fit
    pos[e] = p;                                            // coalesced (e sequential)
}

// ============ kernel 2: per-edge fused layer1(gather+add+relu) + layer2(MFMA) + layer3 ============
// UNCHANGED from R3 (2 m-tiles/wave, 3 waves/SIMD) — serves as the same-session clock
// reference for the chain experiment.  R3 verdict: bound by ~400 MB L2-fill traffic of
// L3-resident Q rows at ~1.7-2 TB/s; occupancy 21.6->32.3% moved dur ~0 -> near its
// structural floor for this formulation.
__global__ __launch_bounds__(256, 3) void edge_kernel(const short* __restrict__ PQ,
                                                      const unsigned int* __restrict__ spk,
                                                      const short* __restrict__ W2s,
                                                      const float* __restrict__ b2,
                                                      const float* __restrict__ W3,
                                                      const float* __restrict__ b3,
                                                      float* __restrict__ tmp) {
    int lane = threadIdx.x & 63;
    int w = threadIdx.x >> 6;
    int e0 = blockIdx.x * 128 + w * 32;
    int m = lane & 15;
    int kq = lane >> 4;

    unsigned int pk = spk[e0 + (lane & 31)];   // 32 packed (row<<16|col), 2-way dup load

    const short* pb[2];
    const short* qb[2];
    #pragma unroll
    for (int t = 0; t < 2; ++t) {
        unsigned int v = __shfl(pk, t * 16 + m, 64);
        int ce = (int)(v & 0xFFFFu);
        int re = (int)(v >> 16);
        pb[t] = PQ + (size_t)ce * 1024 + kq * 8;          // P' half (sorted: ~same line per tile)
        qb[t] = PQ + (size_t)re * 1024 + 512 + kq * 8;    // Q half (random, L3-resident)
    }

    f32x4 acc[2][8];
    #pragma unroll
    for (int t = 0; t < 2; ++t)
        #pragma unroll
        for (int nt = 0; nt < 8; ++nt) acc[t][nt] = (f32x4){0.f, 0.f, 0.f, 0.f};

    #pragma unroll
    for (int kc = 0; kc < 16; ++kc) {
        u32x4 p[2], q[2];
        #pragma unroll
        for (int t = 0; t < 2; ++t) {
            p[t] = *(const u32x4*)(pb[t] + kc * 32);
            q[t] = *(const u32x4*)(qb[t] + kc * 32);
        }
        bf16x8 b[8];
        #pragma unroll
        for (int nt = 0; nt < 8; ++nt)
            b[nt] = *(const bf16x8*)(W2s + (kc * 8 + nt) * 512 + lane * 8);
        #pragma unroll
        for (int t = 0; t < 2; ++t) {
            bf16x8 a = addrelu8(p[t], q[t]);
            #pragma unroll
            for (int nt = 0; nt < 8; ++nt)
                acc[t][nt] = __builtin_amdgcn_mfma_f32_16x16x32_bf16(a, b[nt], acc[t][nt], 0, 0, 0);
        }
    }

    // ---- epilogue: +b2, relu, dot with W3, +b3 (all f32); coalesced f32x4 store ----
    float b2v[8], w3v[8];
    #pragma unroll
    for (int nt = 0; nt < 8; ++nt) {
        b2v[nt] = b2[nt * 16 + m];
        w3v[nt] = W3[nt * 16 + m];
    }
    float b3s = b3[0];
    #pragma unroll
    for (int t = 0; t < 2; ++t) {
        float partial[4] = {0.f, 0.f, 0.f, 0.f};
        #pragma unroll
        for (int nt = 0; nt < 8; ++nt) {
            #pragma unroll
            for (int r = 0; r < 4; ++r) {
                float x2 = acc[t][nt][r] + b2v[nt];       // C row = kq*4+r, col = nt*16+m
                x2 = x2 > 0.f ? x2 : 0.f;
                partial[r] += x2 * w3v[nt];
            }
        }
        #pragma unroll
        for (int r = 0; r < 4; ++r) {
            #pragma unroll
            for (int off = 1; off < 16; off <<= 1)
                partial[r] += __shfl_xor(partial[r], off, 64);
        }
        if (m == 0) {                                     // lanes 0,16,32,48: contiguous 64 B
            f32x4 v;
            #pragma unroll
            for (int r = 0; r < 4; ++r) v[r] = partial[r] + b3s;
            *(f32x4*)(tmp + e0 + t * 16 + kq * 4) = v;
        }
    }
}

// ============ kernel 3: un-permute results to original edge order ============
__global__ __launch_bounds__(256) void permute_kernel(const float* __restrict__ tmp,
                                                      const int* __restrict__ pos,
                                                      float* __restrict__ out) {
    int e = blockIdx.x * 256 + threadIdx.x;                // grid 3125
    out[e] = tmp[pos[e]];
}

extern "C" void kernel_launch(void* const* d_in, const int* in_sizes, int n_in,
                              void* d_out, int out_size, void* d_ws, size_t ws_size,
                              hipStream_t stream) {
    const float* emb = (const float*)d_in[0];
    const int*   ei  = (const int*)d_in[1];
    const float* W1  = (const float*)d_in[2];
    const float* b1  = (const float*)d_in[3];
    const float* W2  = (const float*)d_in[4];
    const float* b2  = (const float*)d_in[5];
    const float* W3  = (const float*)d_in[6];
    const float* b3  = (const float*)d_in[7];
    float* out = (float*)d_out;

    short* PQ   = (short*)((char*)d_ws + PQ_OFF);
    short* W1s  = (short*)((char*)d_ws + W1S_OFF);
    short* W2s  = (short*)((char*)d_ws + W2S_OFF);
    int* counts = (int*)((char*)d_ws + CNT_OFF);
    int* bsum   = (int*)((char*)d_ws + BSUM_OFF);
    unsigned int* spk = (unsigned int*)((char*)d_ws + SPK_OFF);
    int* pos    = (int*)((char*)d_ws + POS_OFF);
    float* tmp  = (float*)((char*)d_ws + TMP_OFF);

    swizzle_kernel<<<96, 256, 0, stream>>>(W1, W2, W1s, W2s);
    // XCD-segmented counting-sort chain
    hipMemsetAsync(counts, 0, SCAN_N * sizeof(int), stream);
    hist_kernel<<<N_EDGES / 256, 256, 0, stream>>>(ei, counts);
    scanA_kernel<<<SCANA_BLOCKS, 256, 0, stream>>>(counts, bsum);
    scanB_kernel<<<1, 256, 0, stream>>>(bsum);
    scanC_kernel<<<SCANA_BLOCKS, 256, 0, stream>>>(counts, bsum);
    scatter_kernel<<<N_EDGES / 256, 256, 0, stream>>>(ei, counts, spk, pos);

    precompute_kernel<<<N_NODESC / 16, 256, 0, stream>>>(emb, W1s, b1, PQ);            // 3125 blocks
    edge_kernel<<<N_EDGES / 128, 256, 0, stream>>>(PQ, spk, W2s, b2, W3, b3, tmp);     // 6250 blocks
    permute_kernel<<<N_EDGES / 256, 256, 0, stream>>>(tmp, pos, out);
}

// Round 5
// 452.909 us; speedup vs baseline: 1.0104x; 1.0104x over previous
//
#include <hip/hip_runtime.h>
#include <hip/hip_bf16.h>
#include <stdint.h>

// Problem constants (fixed by the reference)
#define N_EDGES   800000
#define N_NODESC  50000
#define HID       128

typedef __attribute__((ext_vector_type(8))) short bf16x8;  // 8 bf16 = 4 VGPRs (MFMA A/B frag)
typedef __attribute__((ext_vector_type(4))) float f32x4;   // MFMA C/D frag
typedef __attribute__((ext_vector_type(4))) unsigned int u32x4;

__device__ __forceinline__ short f2bf(float f) {
    union { float f; uint32_t u; } v; v.f = f;
    uint32_t r = v.u + 0x7FFFu + ((v.u >> 16) & 1u);   // round-to-nearest-even
    return (short)(r >> 16);
}

// pack two f32 -> bf16x2 (RNE) via native v_cvt_pk_bf16_f32 on gfx950
__device__ __forceinline__ uint32_t packbf2(float lo, float hi) {
    float2 t; t.x = lo; t.y = hi;
    __hip_bfloat162 h = __float22bfloat162_rn(t);
    uint32_t u;
    __builtin_memcpy(&u, &h, 4);       // __hip_bfloat162 not trivially copyable -> memcpy pun
    return u;
}

// packed bf16x2 (a+b) then relu:
//   __hadd2 -> native v_pk_add_bf16 (one RNE rounding);  relu via sign-mask, exact.
__device__ __forceinline__ uint32_t addrelu2(uint32_t a, uint32_t b) {
    __hip_bfloat162 ha, hb;
    __builtin_memcpy(&ha, &a, 4);
    __builtin_memcpy(&hb, &b, 4);
    __hip_bfloat162 s = __hadd2(ha, hb);
    uint32_t x;
    __builtin_memcpy(&x, &s, 4);
    uint32_t neg = (x & 0x80008000u) >> 15;      // 1 at bit0/bit16 where half negative
    return x & ~(neg * 0xFFFFu);                 // zero negative halves
}
__device__ __forceinline__ bf16x8 addrelu8(u32x4 p, u32x4 q) {
    u32x4 r;
    #pragma unroll
    for (int j = 0; j < 4; ++j) r[j] = addrelu2(p[j], q[j]);
    bf16x8 out;
    __builtin_memcpy(&out, &r, 16);
    return out;
}

// ---------------- workspace layout ----------------
// PQ  : bf16 [50000][1024]  (cols 0..511 = emb@W1_top + b1 "P'", 512..1023 = emb@W1_bot "Q")
// W1s : bf16 frag-major, 4*64 frags x 64 lanes x 8   (B-frags of W1cat [128,1024])
// W2s : bf16 frag-major, 16*8 frags x 64 lanes x 8   (B-frags of W2 [512,128])
// cnt : int[8][50176]  XCD-SEGMENTED histogram -> (after scan) cursor.
//       Storage is seg-major so hist/scatter atomic lines stay XCD-local (R4: -24 us
//       on the chain).  R4 ERROR, fixed here: the SCAN now runs in (col, seg) order
//       (e = col*8 + seg), so placement is ONE globally col-sorted run — R4's (seg,col)
//       order made 8 runs and re-streamed every P-row up to 8x (FETCH 402->559 MB).
//       Atomic layout and placement order are independent; we take the best of both.
// bsum: int[2048]      scanA chunk totals (1568 used)
// spk : uint[800000]   col-sorted edges, packed (row<<16 | col)
// pos : int[800000]    sorted position of original edge e (written coalesced)
// tmp : float[800000]  edge-kernel results in SORTED order (coalesced writes)
#define PQ_OFF    0UL
#define W1S_OFF   102400000UL                 // 50000*1024*2
#define W2S_OFF   (W1S_OFF + 262144UL)        // + 128*1024*2
#define CNT_OFF   (W2S_OFF + 131072UL)        // 102,793,216 ; 8*50176*4 = 1,605,632 B
#define BSUM_OFF  (CNT_OFF + 1605632UL)       // 104,398,848
#define SPK_OFF   (BSUM_OFF + 8192UL)         // 104,407,040
#define POS_OFF   (SPK_OFF + 3200000UL)       // 107,607,040
#define TMP_OFF   (POS_OFF + 3200000UL)       // 110,807,040
// total ws: 114,007,040 bytes (fit proven in R4)

#define NBINS     50176                       // 196*256 (padded)
#define NSEG      8
#define SCAN_N    (NSEG * NBINS)              // 401408 = 1568 * 256
#define SCANA_BLOCKS 1568

// ============ kernel 0: weight convert + B-fragment swizzle ============
// B-frag for 16x16x32 bf16: lane l holds B[k = kc*32 + (l>>4)*8 + j][n = nt*16 + (l&15)], j=0..7
__global__ __launch_bounds__(256) void swizzle_kernel(const float* __restrict__ W1,
                                                      const float* __restrict__ W2,
                                                      short* __restrict__ W1s,
                                                      short* __restrict__ W2s) {
    int t = blockIdx.x * 256 + threadIdx.x;
    int lane = t & 63;
    int kq = lane >> 4;       // 0..3
    int nn = lane & 15;
    if (t < 16384) {          // W1cat: K=128, N=1024 -> kc 0..3, nt 0..63
        int frag = t >> 6;
        int kc = frag >> 6;
        int nt = frag & 63;
        int n = nt * 16 + nn;
        int kbase = kc * 32 + kq * 8;
        bf16x8 v;
        #pragma unroll
        for (int j = 0; j < 8; ++j) {
            int k = kbase + j;
            float f = (n < 512) ? W1[k * 512 + n] : W1[(128 + k) * 512 + (n - 512)];
            v[j] = f2bf(f);
        }
        *(bf16x8*)(W1s + frag * 512 + lane * 8) = v;
    } else if (t < 24576) {   // W2: K=512, N=128 -> kc 0..15, nt 0..7
        int t2 = t - 16384;
        int frag = t2 >> 6;
        int kc = frag >> 3;
        int nt = frag & 7;
        int n = nt * 16 + nn;
        int kbase = kc * 32 + kq * 8;
        bf16x8 v;
        #pragma unroll
        for (int j = 0; j < 8; ++j) v[j] = f2bf(W2[(kbase + j) * HID + n]);
        *(bf16x8*)(W2s + frag * 512 + lane * 8) = v;
    }
}

// ============ kernel 1: PQ = emb @ W1cat (+b1 on P half) ============
// grid 3125 x 256: block = 16 node rows, 4 waves each owning a 256-col slice.
__global__ __launch_bounds__(256) void precompute_kernel(const float* __restrict__ emb,
                                                         const short* __restrict__ W1s,
                                                         const float* __restrict__ b1,
                                                         short* __restrict__ PQ) {
    // per-wave tile: 16 rows x 256 cols bf16; row stride 272 shorts = 544 B
    __shared__ short tile[4][16][272];
    int lane = threadIdx.x & 63;
    int w = threadIdx.x >> 6;
    int nb = blockIdx.x * 16;
    int m = lane & 15;
    int kq = lane >> 4;

    const float* arow = emb + (size_t)(nb + m) * 128 + kq * 8;

    f32x4 acc[16];
    #pragma unroll
    for (int i = 0; i < 16; ++i) acc[i] = (f32x4){0.f, 0.f, 0.f, 0.f};

    #pragma unroll
    for (int kc = 0; kc < 4; ++kc) {
        f32x4 x0 = *(const f32x4*)(arow + kc * 32);
        f32x4 x1 = *(const f32x4*)(arow + kc * 32 + 4);
        u32x4 au;
        au[0] = packbf2(x0[0], x0[1]); au[1] = packbf2(x0[2], x0[3]);
        au[2] = packbf2(x1[0], x1[1]); au[3] = packbf2(x1[2], x1[3]);
        bf16x8 a;
        __builtin_memcpy(&a, &au, 16);
        #pragma unroll
        for (int nt = 0; nt < 16; ++nt) {
            int frag = kc * 64 + (w * 16 + nt);
            bf16x8 b = *(const bf16x8*)(W1s + frag * 512 + lane * 8);
            acc[nt] = __builtin_amdgcn_mfma_f32_16x16x32_bf16(a, b, acc[nt], 0, 0, 0);
        }
    }

    // C/D layout: col = lane&15, row = (lane>>4)*4 + r.  Fold b1 into the P half (n<512).
    #pragma unroll
    for (int nt = 0; nt < 16; ++nt) {
        int n = w * 256 + nt * 16 + m;
        float bias = (n < 512) ? b1[n] : 0.0f;
        #pragma unroll
        for (int r = 0; r < 4; ++r)
            tile[w][kq * 4 + r][nt * 16 + m] = f2bf(acc[nt][r] + bias);
    }

    // Read back row-major and store coalesced: 16 B per lane.
    #pragma unroll
    for (int s = 0; s < 8; ++s) {
        int row = s * 2 + (lane >> 5);
        int chunk = lane & 31;
        bf16x8 v = *(const bf16x8*)(&tile[w][row][chunk * 8]);
        *(bf16x8*)(PQ + (size_t)(nb + row) * 1024 + w * 256 + chunk * 8) = v;
    }
}

// ============ XCD-segmented counting sort; placement order = (col, seg) ============

__global__ __launch_bounds__(256) void hist_kernel(const int* __restrict__ ei,
                                                   int* __restrict__ counts) {
    int e = blockIdx.x * 256 + threadIdx.x;                // grid 3125
    int seg = blockIdx.x & 7;                              // block->XCD is round-robin
    atomicAdd(&counts[seg * NBINS + ei[e]], 1);            // XCD-local line
}

// scanA: exclusive scan per 256-elem chunk of the TRANSPOSED view e = col*8 + seg
// (storage stays seg-major: addr = (e&7)*NBINS + (e>>3)).  Chunk totals -> bsum.
__global__ __launch_bounds__(256) void scanA_kernel(int* __restrict__ counts,
                                                    int* __restrict__ bsum) {
    __shared__ int sm[256];
    int t = threadIdx.x;
    int e = blockIdx.x * 256 + t;                          // grid 1568; block = 32 cols x 8 segs
    int addr = (e & 7) * NBINS + (e >> 3);
    int v = counts[addr];
    sm[t] = v;
    __syncthreads();
    #pragma unroll
    for (int off = 1; off < 256; off <<= 1) {
        int y = (t >= off) ? sm[t - off] : 0;
        __syncthreads();
        sm[t] += y;
        __syncthreads();
    }
    counts[addr] = sm[t] - v;                              // exclusive within chunk
    if (t == 255) bsum[blockIdx.x] = sm[t];
}

// fused scanB+scanC: each block redundantly computes its exclusive base over the 1568
// chunk totals (strided per-thread partial sums + block reduce), then adds it to its
// 256 cursor elems (same transposed mapping as scanA).  counts becomes the cursor.
__global__ __launch_bounds__(256) void finalizeC_kernel(int* __restrict__ counts,
                                                        const int* __restrict__ bsum) {
    __shared__ int wsum[4];
    int t = threadIdx.x;
    int b = blockIdx.x;                                    // grid 1568
    int v = 0;
    for (int idx = t; idx < b; idx += 256) v += bsum[idx]; // exclusive: idx < b
    #pragma unroll
    for (int off = 1; off < 64; off <<= 1) v += __shfl_xor(v, off, 64);
    if ((t & 63) == 0) wsum[t >> 6] = v;
    __syncthreads();
    int base = wsum[0] + wsum[1] + wsum[2] + wsum[3];
    int e = b * 256 + t;
    counts[(e & 7) * NBINS + (e >> 3)] += base;
}

__global__ __launch_bounds__(256) void scatter_kernel(const int* __restrict__ ei,
                                                      int* __restrict__ cursor,
                                                      unsigned int* __restrict__ spk,
                                                      int* __restrict__ pos) {
    int e = blockIdx.x * 256 + threadIdx.x;                // grid 3125
    int seg = blockIdx.x & 7;                              // must match hist_kernel
    int c = ei[e];
    int r = ei[N_EDGES + e];
    int p = atomicAdd(&cursor[seg * NBINS + c], 1);        // XCD-local line; (col,seg) order
    spk[p] = ((unsigned int)r << 16) | (unsigned int)c;    // 50000 < 2^16: both fit
    pos[e] = p;                                            // coalesced (e sequential)
}

// ============ kernel 2: per-edge fused layer1(gather+add+relu) + layer2(MFMA) + layer3 ============
// UNCHANGED since R3 (2 m-tiles/wave, 3 waves/SIMD).  R3/R4 verdict: bound by the
// ~400 MB of L2-miss traffic (random Q rows, L3-resident) at the ~1.7-2.2 TB/s this
// access mix sustains; occupancy 2->3 waves/SIMD moved nothing.  2D (col,row) tiling
// can't beat it for a random deg-16 bipartite graph (panel reload >> touches).
__global__ __launch_bounds__(256, 3) void edge_kernel(const short* __restrict__ PQ,
                                                      const unsigned int* __restrict__ spk,
                                                      const short* __restrict__ W2s,
                                                      const float* __restrict__ b2,
                                                      const float* __restrict__ W3,
                                                      const float* __restrict__ b3,
                                                      float* __restrict__ tmp) {
    int lane = threadIdx.x & 63;
    int w = threadIdx.x >> 6;
    int e0 = blockIdx.x * 128 + w * 32;
    int m = lane & 15;
    int kq = lane >> 4;

    unsigned int pk = spk[e0 + (lane & 31)];   // 32 packed (row<<16|col), 2-way dup load

    const short* pb[2];
    const short* qb[2];
    #pragma unroll
    for (int t = 0; t < 2; ++t) {
        unsigned int v = __shfl(pk, t * 16 + m, 64);
        int ce = (int)(v & 0xFFFFu);
        int re = (int)(v >> 16);
        pb[t] = PQ + (size_t)ce * 1024 + kq * 8;          // P' half (sorted: ~same line per tile)
        qb[t] = PQ + (size_t)re * 1024 + 512 + kq * 8;    // Q half (random, L3-resident)
    }

    f32x4 acc[2][8];
    #pragma unroll
    for (int t = 0; t < 2; ++t)
        #pragma unroll
        for (int nt = 0; nt < 8; ++nt) acc[t][nt] = (f32x4){0.f, 0.f, 0.f, 0.f};

    #pragma unroll
    for (int kc = 0; kc < 16; ++kc) {
        u32x4 p[2], q[2];
        #pragma unroll
        for (int t = 0; t < 2; ++t) {
            p[t] = *(const u32x4*)(pb[t] + kc * 32);
            q[t] = *(const u32x4*)(qb[t] + kc * 32);
        }
        bf16x8 b[8];
        #pragma unroll
        for (int nt = 0; nt < 8; ++nt)
            b[nt] = *(const bf16x8*)(W2s + (kc * 8 + nt) * 512 + lane * 8);
        #pragma unroll
        for (int t = 0; t < 2; ++t) {
            bf16x8 a = addrelu8(p[t], q[t]);
            #pragma unroll
            for (int nt = 0; nt < 8; ++nt)
                acc[t][nt] = __builtin_amdgcn_mfma_f32_16x16x32_bf16(a, b[nt], acc[t][nt], 0, 0, 0);
        }
    }

    // ---- epilogue: +b2, relu, dot with W3, +b3 (all f32); coalesced f32x4 store ----
    float b2v[8], w3v[8];
    #pragma unroll
    for (int nt = 0; nt < 8; ++nt) {
        b2v[nt] = b2[nt * 16 + m];
        w3v[nt] = W3[nt * 16 + m];
    }
    float b3s = b3[0];
    #pragma unroll
    for (int t = 0; t < 2; ++t) {
        float partial[4] = {0.f, 0.f, 0.f, 0.f};
        #pragma unroll
        for (int nt = 0; nt < 8; ++nt) {
            #pragma unroll
            for (int r = 0; r < 4; ++r) {
                float x2 = acc[t][nt][r] + b2v[nt];       // C row = kq*4+r, col = nt*16+m
                x2 = x2 > 0.f ? x2 : 0.f;
                partial[r] += x2 * w3v[nt];
            }
        }
        #pragma unroll
        for (int r = 0; r < 4; ++r) {
            #pragma unroll
            for (int off = 1; off < 16; off <<= 1)
                partial[r] += __shfl_xor(partial[r], off, 64);
        }
        if (m == 0) {                                     // lanes 0,16,32,48: contiguous 64 B
            f32x4 v;
            #pragma unroll
            for (int r = 0; r < 4; ++r) v[r] = partial[r] + b3s;
            *(f32x4*)(tmp + e0 + t * 16 + kq * 4) = v;
        }
    }
}

// ============ kernel 3: un-permute results to original edge order ============
__global__ __launch_bounds__(256) void permute_kernel(const float* __restrict__ tmp,
                                                      const int* __restrict__ pos,
                                                      float* __restrict__ out) {
    int e = blockIdx.x * 256 + threadIdx.x;                // grid 3125
    out[e] = tmp[pos[e]];
}

extern "C" void kernel_launch(void* const* d_in, const int* in_sizes, int n_in,
                              void* d_out, int out_size, void* d_ws, size_t ws_size,
                              hipStream_t stream) {
    const float* emb = (const float*)d_in[0];
    const int*   ei  = (const int*)d_in[1];
    const float* W1  = (const float*)d_in[2];
    const float* b1  = (const float*)d_in[3];
    const float* W2  = (const float*)d_in[4];
    const float* b2  = (const float*)d_in[5];
    const float* W3  = (const float*)d_in[6];
    const float* b3  = (const float*)d_in[7];
    float* out = (float*)d_out;

    short* PQ   = (short*)((char*)d_ws + PQ_OFF);
    short* W1s  = (short*)((char*)d_ws + W1S_OFF);
    short* W2s  = (short*)((char*)d_ws + W2S_OFF);
    int* counts = (int*)((char*)d_ws + CNT_OFF);
    int* bsum   = (int*)((char*)d_ws + BSUM_OFF);
    unsigned int* spk = (unsigned int*)((char*)d_ws + SPK_OFF);
    int* pos    = (int*)((char*)d_ws + POS_OFF);
    float* tmp  = (float*)((char*)d_ws + TMP_OFF);

    swizzle_kernel<<<96, 256, 0, stream>>>(W1, W2, W1s, W2s);
    // XCD-segmented counting-sort chain, (col,seg) placement order
    hipMemsetAsync(counts, 0, SCAN_N * sizeof(int), stream);
    hist_kernel<<<N_EDGES / 256, 256, 0, stream>>>(ei, counts);
    scanA_kernel<<<SCANA_BLOCKS, 256, 0, stream>>>(counts, bsum);
    finalizeC_kernel<<<SCANA_BLOCKS, 256, 0, stream>>>(counts, bsum);
    scatter_kernel<<<N_EDGES / 256, 256, 0, stream>>>(ei, counts, spk, pos);

    precompute_kernel<<<N_NODESC / 16, 256, 0, stream>>>(emb, W1s, b1, PQ);            // 3125 blocks
    edge_kernel<<<N_EDGES / 128, 256, 0, stream>>>(PQ, spk, W2s, b2, W3, b3, tmp);     // 6250 blocks
    permute_kernel<<<N_EDGES / 256, 256, 0, stream>>>(tmp, pos, out);
}

// Round 6
// 449.383 us; speedup vs baseline: 1.0184x; 1.0078x over previous
//
#include <hip/hip_runtime.h>
#include <hip/hip_bf16.h>
#include <stdint.h>

// Problem constants (fixed by the reference)
#define N_EDGES   800000
#define N_NODESC  50000
#define HID       128

typedef __attribute__((ext_vector_type(8))) short bf16x8;  // 8 bf16 = 4 VGPRs (MFMA A/B frag)
typedef __attribute__((ext_vector_type(4))) float f32x4;   // MFMA C/D frag
typedef __attribute__((ext_vector_type(4))) unsigned int u32x4;

__device__ __forceinline__ short f2bf(float f) {
    union { float f; uint32_t u; } v; v.f = f;
    uint32_t r = v.u + 0x7FFFu + ((v.u >> 16) & 1u);   // round-to-nearest-even
    return (short)(r >> 16);
}

// pack two f32 -> bf16x2 (RNE) via native v_cvt_pk_bf16_f32 on gfx950
__device__ __forceinline__ uint32_t packbf2(float lo, float hi) {
    float2 t; t.x = lo; t.y = hi;
    __hip_bfloat162 h = __float22bfloat162_rn(t);
    uint32_t u;
    __builtin_memcpy(&u, &h, 4);       // __hip_bfloat162 not trivially copyable -> memcpy pun
    return u;
}

// packed bf16x2 (a+b) then relu:
//   __hadd2 -> native v_pk_add_bf16 (one RNE rounding);  relu via sign-mask, exact.
__device__ __forceinline__ uint32_t addrelu2(uint32_t a, uint32_t b) {
    __hip_bfloat162 ha, hb;
    __builtin_memcpy(&ha, &a, 4);
    __builtin_memcpy(&hb, &b, 4);
    __hip_bfloat162 s = __hadd2(ha, hb);
    uint32_t x;
    __builtin_memcpy(&x, &s, 4);
    uint32_t neg = (x & 0x80008000u) >> 15;      // 1 at bit0/bit16 where half negative
    return x & ~(neg * 0xFFFFu);                 // zero negative halves
}
__device__ __forceinline__ bf16x8 addrelu8(u32x4 p, u32x4 q) {
    u32x4 r;
    #pragma unroll
    for (int j = 0; j < 4; ++j) r[j] = addrelu2(p[j], q[j]);
    bf16x8 out;
    __builtin_memcpy(&out, &r, 16);
    return out;
}

// ---------------- workspace layout ----------------
// PQ  : bf16 [50000][1024]  (cols 0..511 = emb@W1_top + b1 "P'", 512..1023 = emb@W1_bot "Q")
// W1s : bf16 frag-major, 4*64 frags x 64 lanes x 8   (B-frags of W1cat [128,1024])
// W2s : bf16 frag-major, 16*8 frags x 64 lanes x 8   (B-frags of W2 [512,128])
// cnt : int[128][3136]  per-block bin counts -> (after scan) per-block bin cursors.
//       R5 post-mortem: the full counting sort's 1.6M GLOBAL atomics (hist+scatter)
//       were the ~135 us chain cost — net NEGATIVE vs no sort (R0 rest=80 us).
//       This round: COARSE sort by bin = col>>4 (3136 bins) with per-block LDS
//       histograms/cursors — zero global atomics, zero memset.  16-col bins keep a
//       16 KB P-window per ~256-edge bin: P-side dedup ~= full sort.
// bsum: int[2048]      scan chunk totals (1568 used)
// spk : uint[800000]   bin-sorted edges, packed (row<<16 | col)
// pos : int[800000]    sorted position of original edge e (written coalesced)
// tmp : float[800000]  edge-kernel results in SORTED order (coalesced writes)
#define PQ_OFF    0UL
#define W1S_OFF   102400000UL                 // 50000*1024*2
#define W2S_OFF   (W1S_OFF + 262144UL)        // + 128*1024*2
#define CNT_OFF   (W2S_OFF + 131072UL)        // 102,793,216 ; 128*3136*4 = 1,605,632 B
#define BSUM_OFF  (CNT_OFF + 1605632UL)       // 104,398,848
#define SPK_OFF   (BSUM_OFF + 8192UL)         // 104,407,040
#define POS_OFF   (SPK_OFF + 3200000UL)       // 107,607,040
#define TMP_OFF   (POS_OFF + 3200000UL)       // 110,807,040
// total ws: 114,007,040 bytes (fit proven in R4/R5)

#define NBIN2     3136                        // ceil(50000/16) padded; col>>4 < 3125
#define NBLK2     128                         // hist/scatter blocks
#define EPB       (N_EDGES / NBLK2)           // 6250 edges per block
#define SCAN_N    (NBIN2 * NBLK2)             // 401408 = 1568 * 256
#define SCAN_BLOCKS 1568

// ============ kernel 0: weight convert + B-fragment swizzle ============
// B-frag for 16x16x32 bf16: lane l holds B[k = kc*32 + (l>>4)*8 + j][n = nt*16 + (l&15)], j=0..7
__global__ __launch_bounds__(256) void swizzle_kernel(const float* __restrict__ W1,
                                                      const float* __restrict__ W2,
                                                      short* __restrict__ W1s,
                                                      short* __restrict__ W2s) {
    int t = blockIdx.x * 256 + threadIdx.x;
    int lane = t & 63;
    int kq = lane >> 4;       // 0..3
    int nn = lane & 15;
    if (t < 16384) {          // W1cat: K=128, N=1024 -> kc 0..3, nt 0..63
        int frag = t >> 6;
        int kc = frag >> 6;
        int nt = frag & 63;
        int n = nt * 16 + nn;
        int kbase = kc * 32 + kq * 8;
        bf16x8 v;
        #pragma unroll
        for (int j = 0; j < 8; ++j) {
            int k = kbase + j;
            float f = (n < 512) ? W1[k * 512 + n] : W1[(128 + k) * 512 + (n - 512)];
            v[j] = f2bf(f);
        }
        *(bf16x8*)(W1s + frag * 512 + lane * 8) = v;
    } else if (t < 24576) {   // W2: K=512, N=128 -> kc 0..15, nt 0..7
        int t2 = t - 16384;
        int frag = t2 >> 6;
        int kc = frag >> 3;
        int nt = frag & 7;
        int n = nt * 16 + nn;
        int kbase = kc * 32 + kq * 8;
        bf16x8 v;
        #pragma unroll
        for (int j = 0; j < 8; ++j) v[j] = f2bf(W2[(kbase + j) * HID + n]);
        *(bf16x8*)(W2s + frag * 512 + lane * 8) = v;
    }
}

// ============ kernel 1: PQ = emb @ W1cat (+b1 on P half) ============
// grid 3125 x 256: block = 16 node rows, 4 waves each owning a 256-col slice.
__global__ __launch_bounds__(256) void precompute_kernel(const float* __restrict__ emb,
                                                         const short* __restrict__ W1s,
                                                         const float* __restrict__ b1,
                                                         short* __restrict__ PQ) {
    // per-wave tile: 16 rows x 256 cols bf16; row stride 272 shorts = 544 B
    __shared__ short tile[4][16][272];
    int lane = threadIdx.x & 63;
    int w = threadIdx.x >> 6;
    int nb = blockIdx.x * 16;
    int m = lane & 15;
    int kq = lane >> 4;

    const float* arow = emb + (size_t)(nb + m) * 128 + kq * 8;

    f32x4 acc[16];
    #pragma unroll
    for (int i = 0; i < 16; ++i) acc[i] = (f32x4){0.f, 0.f, 0.f, 0.f};

    #pragma unroll
    for (int kc = 0; kc < 4; ++kc) {
        f32x4 x0 = *(const f32x4*)(arow + kc * 32);
        f32x4 x1 = *(const f32x4*)(arow + kc * 32 + 4);
        u32x4 au;
        au[0] = packbf2(x0[0], x0[1]); au[1] = packbf2(x0[2], x0[3]);
        au[2] = packbf2(x1[0], x1[1]); au[3] = packbf2(x1[2], x1[3]);
        bf16x8 a;
        __builtin_memcpy(&a, &au, 16);
        #pragma unroll
        for (int nt = 0; nt < 16; ++nt) {
            int frag = kc * 64 + (w * 16 + nt);
            bf16x8 b = *(const bf16x8*)(W1s + frag * 512 + lane * 8);
            acc[nt] = __builtin_amdgcn_mfma_f32_16x16x32_bf16(a, b, acc[nt], 0, 0, 0);
        }
    }

    // C/D layout: col = lane&15, row = (lane>>4)*4 + r.  Fold b1 into the P half (n<512).
    #pragma unroll
    for (int nt = 0; nt < 16; ++nt) {
        int n = w * 256 + nt * 16 + m;
        float bias = (n < 512) ? b1[n] : 0.0f;
        #pragma unroll
        for (int r = 0; r < 4; ++r)
            tile[w][kq * 4 + r][nt * 16 + m] = f2bf(acc[nt][r] + bias);
    }

    // Read back row-major and store coalesced: 16 B per lane.
    #pragma unroll
    for (int s = 0; s < 8; ++s) {
        int row = s * 2 + (lane >> 5);
        int chunk = lane & 31;
        bf16x8 v = *(const bf16x8*)(&tile[w][row][chunk * 8]);
        *(bf16x8*)(PQ + (size_t)(nb + row) * 1024 + w * 256 + chunk * 8) = v;
    }
}

// ============ LDS-binned coarse counting sort (bin = col>>4), ZERO global atomics ============

// binhist: each of 128 blocks histograms its 6250 edges into a private LDS histogram,
// then dumps counts coalesced to cnt[blk][bin].
__global__ __launch_bounds__(256) void binhist_kernel(const int* __restrict__ ei,
                                                      int* __restrict__ cnt) {
    __shared__ int h[NBIN2];
    int t = threadIdx.x;
    int b = blockIdx.x;
    for (int i = t; i < NBIN2; i += 256) h[i] = 0;
    __syncthreads();
    int base = b * EPB;
    for (int i = t; i < EPB; i += 256)
        atomicAdd(&h[ei[base + i] >> 4], 1);               // LDS atomic
    __syncthreads();
    for (int i = t; i < NBIN2; i += 256) cnt[b * NBIN2 + i] = h[i];
}

// scanA: exclusive scan per 256-elem chunk in LOGICAL (bin, blk) order
// L = bin*128 + blk ; storage is block-major: addr = (L&127)*NBIN2 + (L>>7).
__global__ __launch_bounds__(256) void scanA_kernel(int* __restrict__ cnt,
                                                    int* __restrict__ bsum) {
    __shared__ int sm[256];
    int t = threadIdx.x;
    int L = blockIdx.x * 256 + t;                          // grid 1568
    int addr = (L & (NBLK2 - 1)) * NBIN2 + (L >> 7);
    int v = cnt[addr];
    sm[t] = v;
    __syncthreads();
    #pragma unroll
    for (int off = 1; off < 256; off <<= 1) {
        int y = (t >= off) ? sm[t - off] : 0;
        __syncthreads();
        sm[t] += y;
        __syncthreads();
    }
    cnt[addr] = sm[t] - v;                                 // exclusive within chunk
    if (t == 255) bsum[blockIdx.x] = sm[t];
}

// finalizeC: each block redundantly computes its exclusive base over the 1568 chunk
// totals and adds it to its 256 cursor elems (same (bin,blk) mapping as scanA).
__global__ __launch_bounds__(256) void finalizeC_kernel(int* __restrict__ cnt,
                                                        const int* __restrict__ bsum) {
    __shared__ int wsum[4];
    int t = threadIdx.x;
    int b = blockIdx.x;                                    // grid 1568
    int v = 0;
    for (int idx = t; idx < b; idx += 256) v += bsum[idx]; // exclusive: idx < b
    #pragma unroll
    for (int off = 1; off < 64; off <<= 1) v += __shfl_xor(v, off, 64);
    if ((t & 63) == 0) wsum[t >> 6] = v;
    __syncthreads();
    int base = wsum[0] + wsum[1] + wsum[2] + wsum[3];
    int L = b * 256 + t;
    cnt[(L & (NBLK2 - 1)) * NBIN2 + (L >> 7)] += base;
}

// binscatter: block reloads its cursor row into LDS, places its 6250 edges via LDS
// atomics.  Intra-bin order arbitrary (each edge's result returns via pos/permute).
__global__ __launch_bounds__(256) void binscatter_kernel(const int* __restrict__ ei,
                                                         const int* __restrict__ cnt,
                                                         unsigned int* __restrict__ spk,
                                                         int* __restrict__ pos) {
    __shared__ int cur[NBIN2];
    int t = threadIdx.x;
    int b = blockIdx.x;
    for (int i = t; i < NBIN2; i += 256) cur[i] = cnt[b * NBIN2 + i];
    __syncthreads();
    int base = b * EPB;
    for (int i = t; i < EPB; i += 256) {
        int e = base + i;
        int c = ei[e];
        int r = ei[N_EDGES + e];
        int p = atomicAdd(&cur[c >> 4], 1);                // LDS atomic
        spk[p] = ((unsigned int)r << 16) | (unsigned int)c;  // 50000 < 2^16: both fit
        pos[e] = p;                                        // coalesced (e sequential)
    }
}

// ============ kernel 2: per-edge fused layer1(gather+add+relu) + layer2(MFMA) + layer3 ============
// UNCHANGED since R3 (2 m-tiles/wave, 3 waves/SIMD) — same-session clock reference.
// R3/R5 verdict: bound by ~400 MB of L2-miss traffic (random Q rows, L3-resident) at
// the ~1.7-2.2 TB/s this access mix sustains.
__global__ __launch_bounds__(256, 3) void edge_kernel(const short* __restrict__ PQ,
                                                      const unsigned int* __restrict__ spk,
                                                      const short* __restrict__ W2s,
                                                      const float* __restrict__ b2,
                                                      const float* __restrict__ W3,
                                                      const float* __restrict__ b3,
                                                      float* __restrict__ tmp) {
    int lane = threadIdx.x & 63;
    int w = threadIdx.x >> 6;
    int e0 = blockIdx.x * 128 + w * 32;
    int m = lane & 15;
    int kq = lane >> 4;

    unsigned int pk = spk[e0 + (lane & 31)];   // 32 packed (row<<16|col), 2-way dup load

    const short* pb[2];
    const short* qb[2];
    #pragma unroll
    for (int t = 0; t < 2; ++t) {
        unsigned int v = __shfl(pk, t * 16 + m, 64);
        int ce = (int)(v & 0xFFFFu);
        int re = (int)(v >> 16);
        pb[t] = PQ + (size_t)ce * 1024 + kq * 8;          // P' half (binned: shared 16 KB window)
        qb[t] = PQ + (size_t)re * 1024 + 512 + kq * 8;    // Q half (random, L3-resident)
    }

    f32x4 acc[2][8];
    #pragma unroll
    for (int t = 0; t < 2; ++t)
        #pragma unroll
        for (int nt = 0; nt < 8; ++nt) acc[t][nt] = (f32x4){0.f, 0.f, 0.f, 0.f};

    #pragma unroll
    for (int kc = 0; kc < 16; ++kc) {
        u32x4 p[2], q[2];
        #pragma unroll
        for (int t = 0; t < 2; ++t) {
            p[t] = *(const u32x4*)(pb[t] + kc * 32);
            q[t] = *(const u32x4*)(qb[t] + kc * 32);
        }
        bf16x8 b[8];
        #pragma unroll
        for (int nt = 0; nt < 8; ++nt)
            b[nt] = *(const bf16x8*)(W2s + (kc * 8 + nt) * 512 + lane * 8);
        #pragma unroll
        for (int t = 0; t < 2; ++t) {
            bf16x8 a = addrelu8(p[t], q[t]);
            #pragma unroll
            for (int nt = 0; nt < 8; ++nt)
                acc[t][nt] = __builtin_amdgcn_mfma_f32_16x16x32_bf16(a, b[nt], acc[t][nt], 0, 0, 0);
        }
    }

    // ---- epilogue: +b2, relu, dot with W3, +b3 (all f32); coalesced f32x4 store ----
    float b2v[8], w3v[8];
    #pragma unroll
    for (int nt = 0; nt < 8; ++nt) {
        b2v[nt] = b2[nt * 16 + m];
        w3v[nt] = W3[nt * 16 + m];
    }
    float b3s = b3[0];
    #pragma unroll
    for (int t = 0; t < 2; ++t) {
        float partial[4] = {0.f, 0.f, 0.f, 0.f};
        #pragma unroll
        for (int nt = 0; nt < 8; ++nt) {
            #pragma unroll
            for (int r = 0; r < 4; ++r) {
                float x2 = acc[t][nt][r] + b2v[nt];       // C row = kq*4+r, col = nt*16+m
                x2 = x2 > 0.f ? x2 : 0.f;
                partial[r] += x2 * w3v[nt];
            }
        }
        #pragma unroll
        for (int r = 0; r < 4; ++r) {
            #pragma unroll
            for (int off = 1; off < 16; off <<= 1)
                partial[r] += __shfl_xor(partial[r], off, 64);
        }
        if (m == 0) {                                     // lanes 0,16,32,48: contiguous 64 B
            f32x4 v;
            #pragma unroll
            for (int r = 0; r < 4; ++r) v[r] = partial[r] + b3s;
            *(f32x4*)(tmp + e0 + t * 16 + kq * 4) = v;
        }
    }
}

// ============ kernel 3: un-permute results to original edge order ============
__global__ __launch_bounds__(256) void permute_kernel(const float* __restrict__ tmp,
                                                      const int* __restrict__ pos,
                                                      float* __restrict__ out) {
    int e = blockIdx.x * 256 + threadIdx.x;                // grid 3125
    out[e] = tmp[pos[e]];
}

extern "C" void kernel_launch(void* const* d_in, const int* in_sizes, int n_in,
                              void* d_out, int out_size, void* d_ws, size_t ws_size,
                              hipStream_t stream) {
    const float* emb = (const float*)d_in[0];
    const int*   ei  = (const int*)d_in[1];
    const float* W1  = (const float*)d_in[2];
    const float* b1  = (const float*)d_in[3];
    const float* W2  = (const float*)d_in[4];
    const float* b2  = (const float*)d_in[5];
    const float* W3  = (const float*)d_in[6];
    const float* b3  = (const float*)d_in[7];
    float* out = (float*)d_out;

    short* PQ   = (short*)((char*)d_ws + PQ_OFF);
    short* W1s  = (short*)((char*)d_ws + W1S_OFF);
    short* W2s  = (short*)((char*)d_ws + W2S_OFF);
    int* cnt    = (int*)((char*)d_ws + CNT_OFF);
    int* bsum   = (int*)((char*)d_ws + BSUM_OFF);
    unsigned int* spk = (unsigned int*)((char*)d_ws + SPK_OFF);
    int* pos    = (int*)((char*)d_ws + POS_OFF);
    float* tmp  = (float*)((char*)d_ws + TMP_OFF);

    swizzle_kernel<<<96, 256, 0, stream>>>(W1, W2, W1s, W2s);
    // LDS-binned coarse sort chain: no memset, no global atomics
    binhist_kernel<<<NBLK2, 256, 0, stream>>>(ei, cnt);
    scanA_kernel<<<SCAN_BLOCKS, 256, 0, stream>>>(cnt, bsum);
    finalizeC_kernel<<<SCAN_BLOCKS, 256, 0, stream>>>(cnt, bsum);
    binscatter_kernel<<<NBLK2, 256, 0, stream>>>(ei, cnt, spk, pos);

    precompute_kernel<<<N_NODESC / 16, 256, 0, stream>>>(emb, W1s, b1, PQ);            // 3125 blocks
    edge_kernel<<<N_EDGES / 128, 256, 0, stream>>>(PQ, spk, W2s, b2, W3, b3, tmp);     // 6250 blocks
    permute_kernel<<<N_EDGES / 256, 256, 0, stream>>>(tmp, pos, out);
}

// Round 7
// 422.068 us; speedup vs baseline: 1.0843x; 1.0647x over previous
//
#include <hip/hip_runtime.h>
#include <hip/hip_bf16.h>
#include <stdint.h>

// Problem constants (fixed by the reference)
#define N_EDGES   800000
#define N_NODESC  50000
#define HID       128

typedef __attribute__((ext_vector_type(8))) short bf16x8;  // 8 bf16 = 4 VGPRs (MFMA A/B frag)
typedef __attribute__((ext_vector_type(4))) float f32x4;   // MFMA C/D frag
typedef __attribute__((ext_vector_type(4))) unsigned int u32x4;

__device__ __forceinline__ short f2bf(float f) {
    union { float f; uint32_t u; } v; v.f = f;
    uint32_t r = v.u + 0x7FFFu + ((v.u >> 16) & 1u);   // round-to-nearest-even
    return (short)(r >> 16);
}

// pack two f32 -> bf16x2 (RNE) via native v_cvt_pk_bf16_f32 on gfx950
__device__ __forceinline__ uint32_t packbf2(float lo, float hi) {
    float2 t; t.x = lo; t.y = hi;
    __hip_bfloat162 h = __float22bfloat162_rn(t);
    uint32_t u;
    __builtin_memcpy(&u, &h, 4);       // __hip_bfloat162 not trivially copyable -> memcpy pun
    return u;
}

// packed bf16x2 (a+b) then relu:
//   __hadd2 -> native v_pk_add_bf16 (one RNE rounding);  relu via sign-mask, exact.
__device__ __forceinline__ uint32_t addrelu2(uint32_t a, uint32_t b) {
    __hip_bfloat162 ha, hb;
    __builtin_memcpy(&ha, &a, 4);
    __builtin_memcpy(&hb, &b, 4);
    __hip_bfloat162 s = __hadd2(ha, hb);
    uint32_t x;
    __builtin_memcpy(&x, &s, 4);
    uint32_t neg = (x & 0x80008000u) >> 15;      // 1 at bit0/bit16 where half negative
    return x & ~(neg * 0xFFFFu);                 // zero negative halves
}
__device__ __forceinline__ bf16x8 addrelu8(u32x4 p, u32x4 q) {
    u32x4 r;
    #pragma unroll
    for (int j = 0; j < 4; ++j) r[j] = addrelu2(p[j], q[j]);
    bf16x8 out;
    __builtin_memcpy(&out, &r, 16);
    return out;
}

// ---------------- workspace layout ----------------
// SORT LINE ABANDONED (R1-R6 ledger): full sort saves 78 us of edge but its chain
// costs >=134; coarse LDS sort costs 78 but saves only 25.  Every variant lost to
// the no-sort R0 baseline (396.6), whose non-edge cost (~80 us) is already at the
// BW floor.  This round: R0 structure + the one unexplored edge lever (occupancy).
//
// PQ  : bf16 [50000][1024]  (cols 0..511 = emb@W1_top + b1 "P'", 512..1023 = emb@W1_bot "Q")
// W1s : bf16 frag-major, 4*64 frags x 64 lanes x 8   (B-frags of W1cat [128,1024])
// W2s : bf16 frag-major, 16*8 frags x 64 lanes x 8   (B-frags of W2 [512,128])
#define PQ_OFF    0UL
#define W1S_OFF   102400000UL                 // 50000*1024*2
#define W2S_OFF   (W1S_OFF + 262144UL)        // + 128*1024*2
// total ws needed: 102,924,288 bytes

// ============ kernel 0: weight convert + B-fragment swizzle ============
// B-frag for 16x16x32 bf16: lane l holds B[k = kc*32 + (l>>4)*8 + j][n = nt*16 + (l&15)], j=0..7
__global__ __launch_bounds__(256) void swizzle_kernel(const float* __restrict__ W1,
                                                      const float* __restrict__ W2,
                                                      short* __restrict__ W1s,
                                                      short* __restrict__ W2s) {
    int t = blockIdx.x * 256 + threadIdx.x;
    int lane = t & 63;
    int kq = lane >> 4;       // 0..3
    int nn = lane & 15;
    if (t < 16384) {          // W1cat: K=128, N=1024 -> kc 0..3, nt 0..63
        int frag = t >> 6;
        int kc = frag >> 6;
        int nt = frag & 63;
        int n = nt * 16 + nn;
        int kbase = kc * 32 + kq * 8;
        bf16x8 v;
        #pragma unroll
        for (int j = 0; j < 8; ++j) {
            int k = kbase + j;
            float f = (n < 512) ? W1[k * 512 + n] : W1[(128 + k) * 512 + (n - 512)];
            v[j] = f2bf(f);
        }
        *(bf16x8*)(W1s + frag * 512 + lane * 8) = v;
    } else if (t < 24576) {   // W2: K=512, N=128 -> kc 0..15, nt 0..7
        int t2 = t - 16384;
        int frag = t2 >> 6;
        int kc = frag >> 3;
        int nt = frag & 7;
        int n = nt * 16 + nn;
        int kbase = kc * 32 + kq * 8;
        bf16x8 v;
        #pragma unroll
        for (int j = 0; j < 8; ++j) v[j] = f2bf(W2[(kbase + j) * HID + n]);
        *(bf16x8*)(W2s + frag * 512 + lane * 8) = v;
    }
}

// ============ kernel 1: PQ = emb @ W1cat (+b1 on P half) ============
// grid 3125 x 256: block = 16 node rows, 4 waves each owning a 256-col slice.
__global__ __launch_bounds__(256) void precompute_kernel(const float* __restrict__ emb,
                                                         const short* __restrict__ W1s,
                                                         const float* __restrict__ b1,
                                                         short* __restrict__ PQ) {
    // per-wave tile: 16 rows x 256 cols bf16; row stride 272 shorts = 544 B
    __shared__ short tile[4][16][272];
    int lane = threadIdx.x & 63;
    int w = threadIdx.x >> 6;
    int nb = blockIdx.x * 16;
    int m = lane & 15;
    int kq = lane >> 4;

    const float* arow = emb + (size_t)(nb + m) * 128 + kq * 8;

    f32x4 acc[16];
    #pragma unroll
    for (int i = 0; i < 16; ++i) acc[i] = (f32x4){0.f, 0.f, 0.f, 0.f};

    #pragma unroll
    for (int kc = 0; kc < 4; ++kc) {
        f32x4 x0 = *(const f32x4*)(arow + kc * 32);
        f32x4 x1 = *(const f32x4*)(arow + kc * 32 + 4);
        u32x4 au;
        au[0] = packbf2(x0[0], x0[1]); au[1] = packbf2(x0[2], x0[3]);
        au[2] = packbf2(x1[0], x1[1]); au[3] = packbf2(x1[2], x1[3]);
        bf16x8 a;
        __builtin_memcpy(&a, &au, 16);
        #pragma unroll
        for (int nt = 0; nt < 16; ++nt) {
            int frag = kc * 64 + (w * 16 + nt);
            bf16x8 b = *(const bf16x8*)(W1s + frag * 512 + lane * 8);
            acc[nt] = __builtin_amdgcn_mfma_f32_16x16x32_bf16(a, b, acc[nt], 0, 0, 0);
        }
    }

    // C/D layout: col = lane&15, row = (lane>>4)*4 + r.  Fold b1 into the P half (n<512).
    #pragma unroll
    for (int nt = 0; nt < 16; ++nt) {
        int n = w * 256 + nt * 16 + m;
        float bias = (n < 512) ? b1[n] : 0.0f;
        #pragma unroll
        for (int r = 0; r < 4; ++r)
            tile[w][kq * 4 + r][nt * 16 + m] = f2bf(acc[nt][r] + bias);
    }

    // Read back row-major and store coalesced: 16 B per lane.
    #pragma unroll
    for (int s = 0; s < 8; ++s) {
        int row = s * 2 + (lane >> 5);
        int chunk = lane & 31;
        bf16x8 v = *(const bf16x8*)(&tile[w][row][chunk * 8]);
        *(bf16x8*)(PQ + (size_t)(nb + row) * 1024 + w * 256 + chunk * 8) = v;
    }
}

// ============ kernel 2: per-edge fused layer1(gather+add+relu) + layer2(MFMA) + layer3 ============
// R7: R0's unsorted structure + the T=2 body (proven bit-identical in R3-R6).
// R0 ran T=4: acc=128 AGPR + 128 VGPR = hard 2 waves/SIMD, ~60% stall on random-L3
// (~600ns) gathers.  T=2 (64 AGPR, VGPR 84 measured) natively fits 3 waves/SIMD.
// R3 showed occupancy doesn't help the SORTED kernel (L2-traffic-bound at 1.7 TB/s)
// — but unsorted is LATENCY-bound (731 MB at only ~2.3 TB/s achieved = ~40% pure
// transfer time), the regime where +50% wave concurrency pays.
// No sort, no permute: indices straight from ei, results straight to out.
__global__ __launch_bounds__(256, 3) void edge_kernel(const short* __restrict__ PQ,
                                                      const int* __restrict__ ei,
                                                      const short* __restrict__ W2s,
                                                      const float* __restrict__ b2,
                                                      const float* __restrict__ W3,
                                                      const float* __restrict__ b3,
                                                      float* __restrict__ out) {
    int lane = threadIdx.x & 63;
    int w = threadIdx.x >> 6;
    int e0 = blockIdx.x * 128 + w * 32;
    int m = lane & 15;
    int kq = lane >> 4;

    // 32 col indices + 32 row indices (lanes 0..31 live, 32..63 duplicate)
    int idx_c = ei[e0 + (lane & 31)];
    int idx_r = ei[N_EDGES + e0 + (lane & 31)];

    const short* pb[2];
    const short* qb[2];
    #pragma unroll
    for (int t = 0; t < 2; ++t) {
        int ce = __shfl(idx_c, t * 16 + m, 64);
        int re = __shfl(idx_r, t * 16 + m, 64);
        pb[t] = PQ + (size_t)ce * 1024 + kq * 8;          // P' half
        qb[t] = PQ + (size_t)re * 1024 + 512 + kq * 8;    // Q half
    }

    f32x4 acc[2][8];
    #pragma unroll
    for (int t = 0; t < 2; ++t)
        #pragma unroll
        for (int nt = 0; nt < 8; ++nt) acc[t][nt] = (f32x4){0.f, 0.f, 0.f, 0.f};

    #pragma unroll
    for (int kc = 0; kc < 16; ++kc) {
        u32x4 p[2], q[2];
        #pragma unroll
        for (int t = 0; t < 2; ++t) {
            p[t] = *(const u32x4*)(pb[t] + kc * 32);
            q[t] = *(const u32x4*)(qb[t] + kc * 32);
        }
        bf16x8 b[8];
        #pragma unroll
        for (int nt = 0; nt < 8; ++nt)
            b[nt] = *(const bf16x8*)(W2s + (kc * 8 + nt) * 512 + lane * 8);
        #pragma unroll
        for (int t = 0; t < 2; ++t) {
            bf16x8 a = addrelu8(p[t], q[t]);
            #pragma unroll
            for (int nt = 0; nt < 8; ++nt)
                acc[t][nt] = __builtin_amdgcn_mfma_f32_16x16x32_bf16(a, b[nt], acc[t][nt], 0, 0, 0);
        }
    }

    // ---- epilogue: +b2, relu, dot with W3, +b3 (all f32); coalesced f32x4 store ----
    float b2v[8], w3v[8];
    #pragma unroll
    for (int nt = 0; nt < 8; ++nt) {
        b2v[nt] = b2[nt * 16 + m];
        w3v[nt] = W3[nt * 16 + m];
    }
    float b3s = b3[0];
    #pragma unroll
    for (int t = 0; t < 2; ++t) {
        float partial[4] = {0.f, 0.f, 0.f, 0.f};
        #pragma unroll
        for (int nt = 0; nt < 8; ++nt) {
            #pragma unroll
            for (int r = 0; r < 4; ++r) {
                float x2 = acc[t][nt][r] + b2v[nt];       // C row = kq*4+r, col = nt*16+m
                x2 = x2 > 0.f ? x2 : 0.f;
                partial[r] += x2 * w3v[nt];
            }
        }
        #pragma unroll
        for (int r = 0; r < 4; ++r) {
            #pragma unroll
            for (int off = 1; off < 16; off <<= 1)
                partial[r] += __shfl_xor(partial[r], off, 64);
        }
        if (m == 0) {                                     // lanes 0,16,32,48: contiguous 64 B
            f32x4 v;
            #pragma unroll
            for (int r = 0; r < 4; ++r) v[r] = partial[r] + b3s;
            *(f32x4*)(out + e0 + t * 16 + kq * 4) = v;
        }
    }
}

extern "C" void kernel_launch(void* const* d_in, const int* in_sizes, int n_in,
                              void* d_out, int out_size, void* d_ws, size_t ws_size,
                              hipStream_t stream) {
    const float* emb = (const float*)d_in[0];
    const int*   ei  = (const int*)d_in[1];
    const float* W1  = (const float*)d_in[2];
    const float* b1  = (const float*)d_in[3];
    const float* W2  = (const float*)d_in[4];
    const float* b2  = (const float*)d_in[5];
    const float* W3  = (const float*)d_in[6];
    const float* b3  = (const float*)d_in[7];
    float* out = (float*)d_out;

    short* PQ  = (short*)((char*)d_ws + PQ_OFF);
    short* W1s = (short*)((char*)d_ws + W1S_OFF);
    short* W2s = (short*)((char*)d_ws + W2S_OFF);

    swizzle_kernel<<<96, 256, 0, stream>>>(W1, W2, W1s, W2s);
    precompute_kernel<<<N_NODESC / 16, 256, 0, stream>>>(emb, W1s, b1, PQ);            // 3125 blocks
    edge_kernel<<<N_EDGES / 128, 256, 0, stream>>>(PQ, ei, W2s, b2, W3, b3, out);      // 6250 blocks
}

// Round 8
// 419.805 us; speedup vs baseline: 1.0901x; 1.0054x over previous
//
#include <hip/hip_runtime.h>
#include <hip/hip_bf16.h>
#include <stdint.h>

// Problem constants (fixed by the reference)
#define N_EDGES   800000
#define N_NODESC  50000
#define HID       128

typedef __attribute__((ext_vector_type(8))) short bf16x8;  // 8 bf16 = 4 VGPRs (MFMA A/B frag)
typedef __attribute__((ext_vector_type(4))) float f32x4;   // MFMA C/D frag
typedef __attribute__((ext_vector_type(4))) unsigned int u32x4;

__device__ __forceinline__ short f2bf(float f) {
    union { float f; uint32_t u; } v; v.f = f;
    uint32_t r = v.u + 0x7FFFu + ((v.u >> 16) & 1u);   // round-to-nearest-even
    return (short)(r >> 16);
}

// pack two f32 -> bf16x2 (RNE) via native v_cvt_pk_bf16_f32 on gfx950
__device__ __forceinline__ uint32_t packbf2(float lo, float hi) {
    float2 t; t.x = lo; t.y = hi;
    __hip_bfloat162 h = __float22bfloat162_rn(t);
    uint32_t u;
    __builtin_memcpy(&u, &h, 4);       // __hip_bfloat162 not trivially copyable -> memcpy pun
    return u;
}

// packed bf16x2 (a+b) then relu:
//   __hadd2 -> native v_pk_add_bf16 (one RNE rounding);  relu via sign-mask, exact.
__device__ __forceinline__ uint32_t addrelu2(uint32_t a, uint32_t b) {
    __hip_bfloat162 ha, hb;
    __builtin_memcpy(&ha, &a, 4);
    __builtin_memcpy(&hb, &b, 4);
    __hip_bfloat162 s = __hadd2(ha, hb);
    uint32_t x;
    __builtin_memcpy(&x, &s, 4);
    uint32_t neg = (x & 0x80008000u) >> 15;      // 1 at bit0/bit16 where half negative
    return x & ~(neg * 0xFFFFu);                 // zero negative halves
}
__device__ __forceinline__ bf16x8 addrelu8(u32x4 p, u32x4 q) {
    u32x4 r;
    #pragma unroll
    for (int j = 0; j < 4; ++j) r[j] = addrelu2(p[j], q[j]);
    bf16x8 out;
    __builtin_memcpy(&out, &r, 16);
    return out;
}

// ---------------- workspace layout ----------------
// Sort line abandoned (R1-R6 ledger: every sort variant's chain cost >= its edge win).
// R7 showed wave-count occupancy is also a dead end (3 waves/SIMD: fill 2.39->2.52
// TB/s only, FETCH +6% thrash).  R8 probes the last concurrency knob: PER-WAVE
// prefetch depth — more misses in flight per wave, FEWER concurrent wave working
// sets (2 waves/SIMD), so thrash should fall while fill concurrency doubles.
//
// PQ  : bf16 [50000][1024]  (cols 0..511 = emb@W1_top + b1 "P'", 512..1023 = emb@W1_bot "Q")
// W1s : bf16 frag-major, 4*64 frags x 64 lanes x 8   (B-frags of W1cat [128,1024])
// W2s : bf16 frag-major, 16*8 frags x 64 lanes x 8   (B-frags of W2 [512,128])
#define PQ_OFF    0UL
#define W1S_OFF   102400000UL                 // 50000*1024*2
#define W2S_OFF   (W1S_OFF + 262144UL)        // + 128*1024*2
// total ws needed: 102,924,288 bytes

// ============ kernel 0: weight convert + B-fragment swizzle ============
// B-frag for 16x16x32 bf16: lane l holds B[k = kc*32 + (l>>4)*8 + j][n = nt*16 + (l&15)], j=0..7
__global__ __launch_bounds__(256) void swizzle_kernel(const float* __restrict__ W1,
                                                      const float* __restrict__ W2,
                                                      short* __restrict__ W1s,
                                                      short* __restrict__ W2s) {
    int t = blockIdx.x * 256 + threadIdx.x;
    int lane = t & 63;
    int kq = lane >> 4;       // 0..3
    int nn = lane & 15;
    if (t < 16384) {          // W1cat: K=128, N=1024 -> kc 0..3, nt 0..63
        int frag = t >> 6;
        int kc = frag >> 6;
        int nt = frag & 63;
        int n = nt * 16 + nn;
        int kbase = kc * 32 + kq * 8;
        bf16x8 v;
        #pragma unroll
        for (int j = 0; j < 8; ++j) {
            int k = kbase + j;
            float f = (n < 512) ? W1[k * 512 + n] : W1[(128 + k) * 512 + (n - 512)];
            v[j] = f2bf(f);
        }
        *(bf16x8*)(W1s + frag * 512 + lane * 8) = v;
    } else if (t < 24576) {   // W2: K=512, N=128 -> kc 0..15, nt 0..7
        int t2 = t - 16384;
        int frag = t2 >> 6;
        int kc = frag >> 3;
        int nt = frag & 7;
        int n = nt * 16 + nn;
        int kbase = kc * 32 + kq * 8;
        bf16x8 v;
        #pragma unroll
        for (int j = 0; j < 8; ++j) v[j] = f2bf(W2[(kbase + j) * HID + n]);
        *(bf16x8*)(W2s + frag * 512 + lane * 8) = v;
    }
}

// ============ kernel 1: PQ = emb @ W1cat (+b1 on P half) ============
// grid 3125 x 256: block = 16 node rows, 4 waves each owning a 256-col slice.
__global__ __launch_bounds__(256) void precompute_kernel(const float* __restrict__ emb,
                                                         const short* __restrict__ W1s,
                                                         const float* __restrict__ b1,
                                                         short* __restrict__ PQ) {
    // per-wave tile: 16 rows x 256 cols bf16; row stride 272 shorts = 544 B
    __shared__ short tile[4][16][272];
    int lane = threadIdx.x & 63;
    int w = threadIdx.x >> 6;
    int nb = blockIdx.x * 16;
    int m = lane & 15;
    int kq = lane >> 4;

    const float* arow = emb + (size_t)(nb + m) * 128 + kq * 8;

    f32x4 acc[16];
    #pragma unroll
    for (int i = 0; i < 16; ++i) acc[i] = (f32x4){0.f, 0.f, 0.f, 0.f};

    #pragma unroll
    for (int kc = 0; kc < 4; ++kc) {
        f32x4 x0 = *(const f32x4*)(arow + kc * 32);
        f32x4 x1 = *(const f32x4*)(arow + kc * 32 + 4);
        u32x4 au;
        au[0] = packbf2(x0[0], x0[1]); au[1] = packbf2(x0[2], x0[3]);
        au[2] = packbf2(x1[0], x1[1]); au[3] = packbf2(x1[2], x1[3]);
        bf16x8 a;
        __builtin_memcpy(&a, &au, 16);
        #pragma unroll
        for (int nt = 0; nt < 16; ++nt) {
            int frag = kc * 64 + (w * 16 + nt);
            bf16x8 b = *(const bf16x8*)(W1s + frag * 512 + lane * 8);
            acc[nt] = __builtin_amdgcn_mfma_f32_16x16x32_bf16(a, b, acc[nt], 0, 0, 0);
        }
    }

    // C/D layout: col = lane&15, row = (lane>>4)*4 + r.  Fold b1 into the P half (n<512).
    #pragma unroll
    for (int nt = 0; nt < 16; ++nt) {
        int n = w * 256 + nt * 16 + m;
        float bias = (n < 512) ? b1[n] : 0.0f;
        #pragma unroll
        for (int r = 0; r < 4; ++r)
            tile[w][kq * 4 + r][nt * 16 + m] = f2bf(acc[nt][r] + bias);
    }

    // Read back row-major and store coalesced: 16 B per lane.
    #pragma unroll
    for (int s = 0; s < 8; ++s) {
        int row = s * 2 + (lane >> 5);
        int chunk = lane & 31;
        bf16x8 v = *(const bf16x8*)(&tile[w][row][chunk * 8]);
        *(bf16x8*)(PQ + (size_t)(nb + row) * 1024 + w * 256 + chunk * 8) = v;
    }
}

// ============ kernel 2: per-edge fused layer1(gather+add+relu) + layer2(MFMA) + layer3 ============
// R8: unsorted, T=2, launch_bounds(256,2) + DEPTH-6 explicit circular prefetch of p/q.
// Theory: R7 proved wave-count can't raise the ~2.5 TB/s fill (more waves = more L2
// thrash, FETCH +6%).  Per-wave pipeline depth raises misses-in-flight (8 waves/CU x
// 24 lines = ~192 vs R7's ~96) with FEWER concurrent edges per CU -> less thrash.
// The compiler left 108 regs unused at (256,3); we spend them on the pipeline at
// (256,2).  Static indexing only (rule: runtime-indexed ext_vector arrays -> scratch).
__global__ __launch_bounds__(256, 2) void edge_kernel(const short* __restrict__ PQ,
                                                      const int* __restrict__ ei,
                                                      const short* __restrict__ W2s,
                                                      const float* __restrict__ b2,
                                                      const float* __restrict__ W3,
                                                      const float* __restrict__ b3,
                                                      float* __restrict__ out) {
    int lane = threadIdx.x & 63;
    int w = threadIdx.x >> 6;
    int e0 = blockIdx.x * 128 + w * 32;
    int m = lane & 15;
    int kq = lane >> 4;

    // 32 col indices + 32 row indices (lanes 0..31 live, 32..63 duplicate)
    int idx_c = ei[e0 + (lane & 31)];
    int idx_r = ei[N_EDGES + e0 + (lane & 31)];

    const short* pb[2];
    const short* qb[2];
    #pragma unroll
    for (int t = 0; t < 2; ++t) {
        int ce = __shfl(idx_c, t * 16 + m, 64);
        int re = __shfl(idx_r, t * 16 + m, 64);
        pb[t] = PQ + (size_t)ce * 1024 + kq * 8;          // P' half
        qb[t] = PQ + (size_t)re * 1024 + 512 + kq * 8;    // Q half
    }

    // depth-6 circular prefetch buffers (96 VGPR): all indices compile-time after unroll
    u32x4 pf_p[6][2], pf_q[6][2];
    #pragma unroll
    for (int d = 0; d < 6; ++d) {
        #pragma unroll
        for (int t = 0; t < 2; ++t) {
            pf_p[d][t] = *(const u32x4*)(pb[t] + d * 32);
            pf_q[d][t] = *(const u32x4*)(qb[t] + d * 32);
        }
    }

    f32x4 acc[2][8];
    #pragma unroll
    for (int t = 0; t < 2; ++t)
        #pragma unroll
        for (int nt = 0; nt < 8; ++nt) acc[t][nt] = (f32x4){0.f, 0.f, 0.f, 0.f};

    #pragma unroll
    for (int kc = 0; kc < 16; ++kc) {
        const int slot = kc % 6;                       // literal per unrolled iteration
        u32x4 p[2], q[2];
        #pragma unroll
        for (int t = 0; t < 2; ++t) { p[t] = pf_p[slot][t]; q[t] = pf_q[slot][t]; }
        if (kc + 6 < 16) {                             // issue replacement loads early
            #pragma unroll
            for (int t = 0; t < 2; ++t) {
                pf_p[slot][t] = *(const u32x4*)(pb[t] + (kc + 6) * 32);
                pf_q[slot][t] = *(const u32x4*)(qb[t] + (kc + 6) * 32);
            }
        }
        bf16x8 b[8];
        #pragma unroll
        for (int nt = 0; nt < 8; ++nt)
            b[nt] = *(const bf16x8*)(W2s + (kc * 8 + nt) * 512 + lane * 8);
        #pragma unroll
        for (int t = 0; t < 2; ++t) {
            bf16x8 a = addrelu8(p[t], q[t]);
            #pragma unroll
            for (int nt = 0; nt < 8; ++nt)
                acc[t][nt] = __builtin_amdgcn_mfma_f32_16x16x32_bf16(a, b[nt], acc[t][nt], 0, 0, 0);
        }
    }

    // ---- epilogue: +b2, relu, dot with W3, +b3 (all f32); coalesced f32x4 store ----
    float b2v[8], w3v[8];
    #pragma unroll
    for (int nt = 0; nt < 8; ++nt) {
        b2v[nt] = b2[nt * 16 + m];
        w3v[nt] = W3[nt * 16 + m];
    }
    float b3s = b3[0];
    #pragma unroll
    for (int t = 0; t < 2; ++t) {
        float partial[4] = {0.f, 0.f, 0.f, 0.f};
        #pragma unroll
        for (int nt = 0; nt < 8; ++nt) {
            #pragma unroll
            for (int r = 0; r < 4; ++r) {
                float x2 = acc[t][nt][r] + b2v[nt];       // C row = kq*4+r, col = nt*16+m
                x2 = x2 > 0.f ? x2 : 0.f;
                partial[r] += x2 * w3v[nt];
            }
        }
        #pragma unroll
        for (int r = 0; r < 4; ++r) {
            #pragma unroll
            for (int off = 1; off < 16; off <<= 1)
                partial[r] += __shfl_xor(partial[r], off, 64);
        }
        if (m == 0) {                                     // lanes 0,16,32,48: contiguous 64 B
            f32x4 v;
            #pragma unroll
            for (int r = 0; r < 4; ++r) v[r] = partial[r] + b3s;
            *(f32x4*)(out + e0 + t * 16 + kq * 4) = v;
        }
    }
}

extern "C" void kernel_launch(void* const* d_in, const int* in_sizes, int n_in,
                              void* d_out, int out_size, void* d_ws, size_t ws_size,
                              hipStream_t stream) {
    const float* emb = (const float*)d_in[0];
    const int*   ei  = (const int*)d_in[1];
    const float* W1  = (const float*)d_in[2];
    const float* b1  = (const float*)d_in[3];
    const float* W2  = (const float*)d_in[4];
    const float* b2  = (const float*)d_in[5];
    const float* W3  = (const float*)d_in[6];
    const float* b3  = (const float*)d_in[7];
    float* out = (float*)d_out;

    short* PQ  = (short*)((char*)d_ws + PQ_OFF);
    short* W1s = (short*)((char*)d_ws + W1S_OFF);
    short* W2s = (short*)((char*)d_ws + W2S_OFF);

    swizzle_kernel<<<96, 256, 0, stream>>>(W1, W2, W1s, W2s);
    precompute_kernel<<<N_NODESC / 16, 256, 0, stream>>>(emb, W1s, b1, PQ);            // 3125 blocks
    edge_kernel<<<N_EDGES / 128, 256, 0, stream>>>(PQ, ei, W2s, b2, W3, b3, out);      // 6250 blocks
}